// Round 1
// baseline (11640.205 us; speedup 1.0000x reference)
//
#include <hip/hip_runtime.h>

// ---------------- constants ----------------
#define NS   256   // batch
#define TS   64    // time steps
#define DS   32
#define DA   8
#define DD   512   // model dim
#define HH   8     // heads
#define HD   64    // head dim
#define FF   2048
#define INP  40    // DS+DA
#define INPP 20    // packed pairs of input
#define DP   256   // packed pairs of D
#define KVK  552
#define KVKP 276
#define KVO  1032
#define FFP  1024  // packed pairs of FF

// packed-weight ws offsets (in uint elements, after 128-uint header)
#define OFF_ODE 0
#define SZ_ODE  (256*512)
#define OFF_KV  (OFF_ODE+SZ_ODE)
#define SZ_KV   (276*1032)
#define OFF_IN  (OFF_KV+SZ_KV)
#define SZ_IN   (20*512)
#define OFF_Q   (OFF_IN+SZ_IN)
#define SZ_Q    (256*512)
#define OFF_OUT (OFF_Q+SZ_Q)
#define SZ_OUT  (256*512)
#define OFF_F1  (OFF_OUT+SZ_OUT)
#define SZ_F1   (256*2048)
#define OFF_F2  (OFF_F1+SZ_F1)
#define SZ_F2   (1024*512)
#define OFF_DEC (OFF_F2+SZ_F2)
#define SZ_DEC  (256*32)

#define DEV __device__ __forceinline__

typedef _Float16 half2_t __attribute__((ext_vector_type(2)));

DEV half2_t as_h2(unsigned int u) { return __builtin_bit_cast(half2_t, u); }

DEV float dot2f(unsigned int w, unsigned int x, float acc) {
#if __has_builtin(__builtin_amdgcn_fdot2)
  return __builtin_amdgcn_fdot2(as_h2(w), as_h2(x), acc, false);
#else
  half2_t a = as_h2(w), b = as_h2(x);
  return acc + (float)a[0] * (float)b[0] + (float)a[1] * (float)b[1];
#endif
}

DEV unsigned int pack2f(float a, float b) {
  unsigned short ua = __builtin_bit_cast(unsigned short, (_Float16)a);
  unsigned short ub = __builtin_bit_cast(unsigned short, (_Float16)b);
  return ((unsigned int)ub << 16) | (unsigned int)ua;
}

DEV float fast_tanh(float x) {
  float ax = fabsf(x);
  float e  = __expf(-2.0f * ax);
  float r  = (1.0f - e) / (1.0f + e);
  return copysignf(r, x);
}

DEV float fast_sigmoid(float x) { return 1.0f / (1.0f + __expf(-x)); }

DEV float wave_max(float v) {
  #pragma unroll
  for (int o = 32; o; o >>= 1) v = fmaxf(v, __shfl_xor(v, o));
  return v;
}
DEV float wave_sum(float v) {
  #pragma unroll
  for (int o = 32; o; o >>= 1) v += __shfl_xor(v, o);
  return v;
}

// generic packed matvec column dot: Wp already offset by column j; stride in uints
DEV float dotKP(const unsigned int* __restrict__ Wp, int stride,
                const unsigned int* xq, int KP, float init) {
  float a0 = init, a1 = 0.f;
  #pragma unroll 2
  for (int kp = 0; kp < KP; kp += 4) {
    uint4 xv = *reinterpret_cast<const uint4*>(xq + kp);
    a0 = dot2f(Wp[(kp + 0) * stride], xv.x, a0);
    a1 = dot2f(Wp[(kp + 1) * stride], xv.y, a1);
    a0 = dot2f(Wp[(kp + 2) * stride], xv.z, a0);
    a1 = dot2f(Wp[(kp + 3) * stride], xv.w, a1);
  }
  return a0 + a1;
}

// ---------------- weight f32 -> packed f16 pairs ----------------
__global__ void pack_w_kernel(const float* __restrict__ src, unsigned int* __restrict__ dst,
                              int K2, int Dout) {
  int idx = blockIdx.x * blockDim.x + threadIdx.x;
  int total = K2 * Dout;
  if (idx >= total) return;
  int kp = idx / Dout;
  int j  = idx - kp * Dout;
  float lo = src[(2 * kp) * Dout + j];
  float hi = src[(2 * kp + 1) * Dout + j];
  dst[idx] = pack2f(lo, hi);
}

// ---------------- main persistent per-sample kernel ----------------
__global__ __launch_bounds__(512) void fwp_main(
    const float* __restrict__ states, const float* __restrict__ actions,
    const float* __restrict__ tsteps,
    const float* __restrict__ b_ode, const float* __restrict__ b_in,
    const float* __restrict__ ln_in_g, const float* __restrict__ ln_in_b,
    const float* __restrict__ b_q, const float* __restrict__ b_kv,
    const float* __restrict__ b_out,
    const float* __restrict__ ln_ff_g, const float* __restrict__ ln_ff_b,
    const float* __restrict__ b_ff1, const float* __restrict__ b_ff2,
    const float* __restrict__ b_dec,
    const unsigned int* __restrict__ Wode, const unsigned int* __restrict__ Wkv,
    const unsigned int* __restrict__ Win,  const unsigned int* __restrict__ Wq,
    const unsigned int* __restrict__ Wout, const unsigned int* __restrict__ Wff1,
    const unsigned int* __restrict__ Wff2, const unsigned int* __restrict__ Wdec,
    unsigned int* __restrict__ ctrs, float* __restrict__ outp) {

  const int n = blockIdx.x, tid = threadIdx.x;
  const int w = tid >> 6, lane = tid & 63;

  __shared__ alignas(16) float        sh_h[DD];
  __shared__ alignas(16) unsigned int sh_hp[DP];
  __shared__ alignas(16) unsigned int sh_xp[KVKP];
  __shared__ alignas(16) float        sh_t[DD];
  __shared__ alignas(16) unsigned int sh_p[DP];
  __shared__ alignas(16) float        sh_kvb[KVO];
  __shared__ alignas(16) float        sh_k[DD];
  __shared__ alignas(16) float        sh_v[DD];
  __shared__ alignas(16) float        sh_q[DD];
  __shared__ float                    sh_lr[HH];
  __shared__ alignas(16) float        sh_ff[FF];
  __shared__ alignas(16) unsigned int sh_ffp[FFP];
  __shared__ float                    sh_red[16];
  __shared__ alignas(16) float        sh_decp[512];
  __shared__ int                      sh_flag;

  float W2r[64];
  #pragma unroll
  for (int i = 0; i < 64; ++i) W2r[i] = 0.f;

  sh_h[tid] = 0.f;
  if (tid < DP) sh_hp[tid] = 0u;

  bool pace = true;
  unsigned int* ctr = ctrs + 16 * (n & 7);   // one counter per XCD (blockIdx % 8)

  for (int t = 0; t < TS; ++t) {
    __syncthreads();

    // ---- loose per-XCD pacing barrier (bounded spin; perf-only, deadlock-free)
    if (pace) {
      if (tid == 0) {
        sh_flag = 0;
        __hip_atomic_fetch_add(ctr, 1u, __ATOMIC_RELAXED, __HIP_MEMORY_SCOPE_AGENT);
        unsigned int tgt = 32u * (unsigned int)(t + 1);
        int it = 0;
        while (__hip_atomic_load(ctr, __ATOMIC_RELAXED, __HIP_MEMORY_SCOPE_AGENT) < tgt) {
          if (++it > 4096) { sh_flag = 1; break; }
          __builtin_amdgcn_s_sleep(8);
        }
      }
      __syncthreads();
      if (sh_flag) pace = false;
    }

    // ---- load data (40 inputs -> 20 packed pairs) & dt
    if (tid < INPP) {
      int i0 = 2 * tid, i1 = i0 + 1;
      float a = (i0 < DS) ? states[(n * TS + t) * DS + i0] : actions[(n * TS + t) * DA + (i0 - DS)];
      float b = (i1 < DS) ? states[(n * TS + t) * DS + i1] : actions[(n * TS + t) * DA + (i1 - DS)];
      sh_xp[tid] = pack2f(a, b);
    }
    const float sdt = 0.25f * (tsteps[n * (TS + 1) + t + 1] - tsteps[n * (TS + 1) + t]);

    // ---- ODE: 4 Euler steps, h += sdt * tanh(h @ W_ode + b_ode)
    for (int e = 0; e < 4; ++e) {
      float acc = dotKP(Wode + tid, DD, sh_hp, DP, b_ode[tid]);
      sh_h[tid] += sdt * fast_tanh(acc);      // own element only
      __syncthreads();                        // hp reads done, h written
      if (tid < DP) sh_hp[tid] = pack2f(sh_h[2 * tid], sh_h[2 * tid + 1]);
      __syncthreads();                        // hp ready
    }

    // ---- x = [data, h1] packed
    if (tid < DP) sh_xp[INPP + tid] = sh_hp[tid];
    __syncthreads();

    // ---- kv = x @ W_kv + b_kv   (1032 cols)
    for (int j = tid; j < KVO; j += 512)
      sh_kvb[j] = dotKP(Wkv + j, KVO, sh_xp, KVKP, b_kv[j]);
    __syncthreads();

    // ---- k = softmax(head), v = tanh, lr = sigmoid
    {
      float kx = sh_kvb[tid];
      float km = wave_max(kx);
      float ke = __expf(kx - km);
      float ks = wave_sum(ke);
      sh_k[tid] = ke / ks;
      sh_v[tid] = fast_tanh(sh_kvb[DD + tid]);
      if (tid < HH) sh_lr[tid] = fast_sigmoid(sh_kvb[2 * DD + tid]);
    }

    // ---- q path: LN(data@W_in + b_in) @ W_q + b_q, softmax per head
    float y1 = dotKP(Win + tid, DD, sh_xp, INPP, b_in[tid]);
    {
      float s1 = y1, s2 = y1 * y1;
      #pragma unroll
      for (int o = 32; o; o >>= 1) { s1 += __shfl_xor(s1, o); s2 += __shfl_xor(s2, o); }
      if (lane == 0) { sh_red[2 * w] = s1; sh_red[2 * w + 1] = s2; }
      __syncthreads();
      s1 = 0.f; s2 = 0.f;
      #pragma unroll
      for (int i = 0; i < 8; ++i) { s1 += sh_red[2 * i]; s2 += sh_red[2 * i + 1]; }
      float m  = s1 * (1.0f / DD);
      float va = fmaxf(s2 * (1.0f / DD) - m * m, 0.f);
      float rs = rsqrtf(va + 1e-5f);
      sh_t[tid] = (y1 - m) * rs * ln_in_g[tid] + ln_in_b[tid];
    }
    __syncthreads();
    if (tid < DP) sh_p[tid] = pack2f(sh_t[2 * tid], sh_t[2 * tid + 1]);
    __syncthreads();
    {
      float qraw = dotKP(Wq + tid, DD, sh_p, DP, b_q[tid]);
      float qm = wave_max(qraw);
      float qe = __expf(qraw - qm);
      float qs = wave_sum(qe);
      sh_q[tid] = qe / qs;
    }
    __syncthreads();

    // ---- fused fast-weight update + query (W2 rows in registers)
    {
      float vi  = sh_v[tid];
      float lrw = sh_lr[w];
      float lv  = lrw * vi;
      float acc = 0.f;
      const float* kb = sh_k + w * HD;
      const float* qb = sh_q + w * HD;
      #pragma unroll
      for (int jc = 0; jc < 16; ++jc) {
        float4 k4 = *reinterpret_cast<const float4*>(kb + 4 * jc);
        float4 q4 = *reinterpret_cast<const float4*>(qb + 4 * jc);
        W2r[4 * jc + 0] += lv * k4.x; acc += W2r[4 * jc + 0] * q4.x;
        W2r[4 * jc + 1] += lv * k4.y; acc += W2r[4 * jc + 1] * q4.y;
        W2r[4 * jc + 2] += lv * k4.z; acc += W2r[4 * jc + 2] * q4.z;
        W2r[4 * jc + 3] += lv * k4.w; acc += W2r[4 * jc + 3] * q4.w;
      }
      sh_t[tid] = acc;
    }
    __syncthreads();
    if (tid < DP) sh_p[tid] = pack2f(sh_t[2 * tid], sh_t[2 * tid + 1]);
    __syncthreads();

    // ---- out1 = out @ W_out + b_out
    float o1 = dotKP(Wout + tid, DD, sh_p, DP, b_out[tid]);

    // ---- LN_ff
    {
      float s1 = o1, s2 = o1 * o1;
      #pragma unroll
      for (int o = 32; o; o >>= 1) { s1 += __shfl_xor(s1, o); s2 += __shfl_xor(s2, o); }
      if (lane == 0) { sh_red[2 * w] = s1; sh_red[2 * w + 1] = s2; }
      __syncthreads();
      s1 = 0.f; s2 = 0.f;
      #pragma unroll
      for (int i = 0; i < 8; ++i) { s1 += sh_red[2 * i]; s2 += sh_red[2 * i + 1]; }
      float m  = s1 * (1.0f / DD);
      float va = fmaxf(s2 * (1.0f / DD) - m * m, 0.f);
      float rs = rsqrtf(va + 1e-5f);
      sh_t[tid] = (o1 - m) * rs * ln_ff_g[tid] + ln_ff_b[tid];
    }
    __syncthreads();
    if (tid < DP) sh_p[tid] = pack2f(sh_t[2 * tid], sh_t[2 * tid + 1]);
    __syncthreads();

    // ---- FF1 + relu (2048 cols, 4 per thread)
    {
      float f0 = b_ff1[tid], f1 = b_ff1[tid + 512], f2 = b_ff1[tid + 1024], f3 = b_ff1[tid + 1536];
      #pragma unroll 2
      for (int kp = 0; kp < DP; kp += 2) {
        uint2 xv = *reinterpret_cast<const uint2*>(sh_p + kp);
        const unsigned int* w0 = Wff1 + kp * FF + tid;
        f0 = dot2f(w0[0],    xv.x, f0);
        f1 = dot2f(w0[512],  xv.x, f1);
        f2 = dot2f(w0[1024], xv.x, f2);
        f3 = dot2f(w0[1536], xv.x, f3);
        const unsigned int* w1 = w0 + FF;
        f0 = dot2f(w1[0],    xv.y, f0);
        f1 = dot2f(w1[512],  xv.y, f1);
        f2 = dot2f(w1[1024], xv.y, f2);
        f3 = dot2f(w1[1536], xv.y, f3);
      }
      sh_ff[tid]        = fmaxf(f0, 0.f);
      sh_ff[tid + 512]  = fmaxf(f1, 0.f);
      sh_ff[tid + 1024] = fmaxf(f2, 0.f);
      sh_ff[tid + 1536] = fmaxf(f3, 0.f);
    }
    __syncthreads();
    sh_ffp[tid]       = pack2f(sh_ff[2 * tid], sh_ff[2 * tid + 1]);
    sh_ffp[tid + 512] = pack2f(sh_ff[2 * tid + 1024], sh_ff[2 * tid + 1025]);
    __syncthreads();

    // ---- FF2 + bias + residual -> new h1 (carry)
    {
      float o2 = dotKP(Wff2 + tid, DD, sh_ffp, FFP, b_ff2[tid]) + o1;
      sh_h[tid] = o2;
    }
    __syncthreads();
    if (tid < DP) sh_hp[tid] = pack2f(sh_h[2 * tid], sh_h[2 * tid + 1]);
    __syncthreads();

    // ---- decoder: pred = out @ W_dec + b_dec   (32 cols, 16 k-chunks)
    {
      int col = tid & 31, ch = tid >> 5;
      int kp0 = ch * 16;
      float a = 0.f;
      #pragma unroll
      for (int u = 0; u < 16; u += 4) {
        uint4 xv = *reinterpret_cast<const uint4*>(sh_hp + kp0 + u);
        a = dot2f(Wdec[(kp0 + u + 0) * DS + col], xv.x, a);
        a = dot2f(Wdec[(kp0 + u + 1) * DS + col], xv.y, a);
        a = dot2f(Wdec[(kp0 + u + 2) * DS + col], xv.z, a);
        a = dot2f(Wdec[(kp0 + u + 3) * DS + col], xv.w, a);
      }
      sh_decp[tid] = a;
    }
    __syncthreads();
    if (tid < DS) {
      float s = b_dec[tid];
      #pragma unroll
      for (int c = 0; c < 16; ++c) s += sh_decp[c * 32 + tid];
      outp[(n * TS + t) * DS + tid] = s;
    }
  }
}

// ---------------- host launcher ----------------
extern "C" void kernel_launch(void* const* d_in, const int* in_sizes, int n_in,
                              void* d_out, int out_size, void* d_ws, size_t ws_size,
                              hipStream_t stream) {
  (void)in_sizes; (void)n_in; (void)out_size; (void)ws_size;

  const float* states   = (const float*)d_in[0];
  const float* actions  = (const float*)d_in[1];
  const float* tsteps   = (const float*)d_in[2];
  const float* W_ode    = (const float*)d_in[3];
  const float* b_ode    = (const float*)d_in[4];
  const float* W_in     = (const float*)d_in[5];
  const float* b_in     = (const float*)d_in[6];
  const float* ln_in_g  = (const float*)d_in[7];
  const float* ln_in_b  = (const float*)d_in[8];
  const float* W_q      = (const float*)d_in[9];
  const float* b_q      = (const float*)d_in[10];
  const float* W_kv     = (const float*)d_in[11];
  const float* b_kv     = (const float*)d_in[12];
  const float* W_out    = (const float*)d_in[13];
  const float* b_out    = (const float*)d_in[14];
  const float* ln_ff_g  = (const float*)d_in[15];
  const float* ln_ff_b  = (const float*)d_in[16];
  const float* W_ff1    = (const float*)d_in[17];
  const float* b_ff1    = (const float*)d_in[18];
  const float* W_ff2    = (const float*)d_in[19];
  const float* b_ff2    = (const float*)d_in[20];
  const float* W_dec    = (const float*)d_in[21];
  const float* b_dec    = (const float*)d_in[22];

  unsigned int* wsbase = (unsigned int*)d_ws;
  unsigned int* ctrs   = wsbase;           // 8 counters, 64B apart (512B region)
  unsigned int* W      = wsbase + 128;     // packed weights

  hipMemsetAsync(d_ws, 0, 512, stream);

  auto launch_pack = [&](const float* src, unsigned int* dst, int K2, int Dout) {
    int total = K2 * Dout;
    int blocks = (total + 255) / 256;
    pack_w_kernel<<<blocks, 256, 0, stream>>>(src, dst, K2, Dout);
  };

  launch_pack(W_ode, W + OFF_ODE, 256, 512);
  launch_pack(W_kv,  W + OFF_KV,  276, 1032);
  launch_pack(W_in,  W + OFF_IN,  20,  512);
  launch_pack(W_q,   W + OFF_Q,   256, 512);
  launch_pack(W_out, W + OFF_OUT, 256, 512);
  launch_pack(W_ff1, W + OFF_F1,  256, 2048);
  launch_pack(W_ff2, W + OFF_F2,  1024, 512);
  launch_pack(W_dec, W + OFF_DEC, 256, 32);

  fwp_main<<<NS, 512, 0, stream>>>(
      states, actions, tsteps,
      b_ode, b_in, ln_in_g, ln_in_b, b_q, b_kv, b_out, ln_ff_g, ln_ff_b,
      b_ff1, b_ff2, b_dec,
      W + OFF_ODE, W + OFF_KV, W + OFF_IN, W + OFF_Q,
      W + OFF_OUT, W + OFF_F1, W + OFF_F2, W + OFF_DEC,
      ctrs, (float*)d_out);
}

// Round 2
// 5904.750 us; speedup vs baseline: 1.9713x; 1.9713x over previous
//
#include <hip/hip_runtime.h>

// ---------------- constants ----------------
#define NS   256   // batch
#define TS   64    // time steps
#define DS   32
#define DA   8
#define DD   512   // model dim
#define HH   8     // heads
#define HD   64    // head dim
#define FF   2048
#define INP  40    // DS+DA
#define INPP 20    // packed pairs of input
#define INPG 24    // padded to 3 groups
#define DP   256   // packed pairs of D
#define KVKP 276   // pairs of kv input (552/2)
#define KVKPP 280  // padded to 35 groups
#define KVO  1032
#define FFP  1024  // packed pairs of FF

// packed-weight ws offsets (uint elements, after 128-uint header)
// layout: [KPpad/8][Dout][8]  (8 consecutive k-pairs per column contiguous)
#define OFF_ODE 0
#define SZ_ODE  (32*512*8)
#define OFF_KV  (OFF_ODE+SZ_ODE)
#define SZ_KV   (35*1032*8)
#define OFF_IN  (OFF_KV+SZ_KV)
#define SZ_IN   (3*512*8)
#define OFF_Q   (OFF_IN+SZ_IN)
#define SZ_Q    (32*512*8)
#define OFF_OUT (OFF_Q+SZ_Q)
#define SZ_OUT  (32*512*8)
#define OFF_F1  (OFF_OUT+SZ_OUT)
#define SZ_F1   (32*2048*8)
#define OFF_F2  (OFF_F1+SZ_F1)
#define SZ_F2   (128*512*8)
#define OFF_DEC (OFF_F2+SZ_F2)
#define SZ_DEC  (32*32*8)

#define DEV __device__ __forceinline__

typedef _Float16 half2_t __attribute__((ext_vector_type(2)));

DEV half2_t as_h2(unsigned int u) { return __builtin_bit_cast(half2_t, u); }

DEV float dot2f(unsigned int w, unsigned int x, float acc) {
#if __has_builtin(__builtin_amdgcn_fdot2)
  return __builtin_amdgcn_fdot2(as_h2(w), as_h2(x), acc, false);
#else
  half2_t a = as_h2(w), b = as_h2(x);
  return acc + (float)a[0] * (float)b[0] + (float)a[1] * (float)b[1];
#endif
}

DEV unsigned int pack2f(float a, float b) {
  unsigned short ua = __builtin_bit_cast(unsigned short, (_Float16)a);
  unsigned short ub = __builtin_bit_cast(unsigned short, (_Float16)b);
  return ((unsigned int)ub << 16) | (unsigned int)ua;
}

DEV float fast_tanh(float x) {
  float ax = fabsf(x);
  float e  = __expf(-2.0f * ax);
  float r  = (1.0f - e) / (1.0f + e);
  return copysignf(r, x);
}

DEV float fast_sigmoid(float x) { return 1.0f / (1.0f + __expf(-x)); }

DEV float wave_max(float v) {
  #pragma unroll
  for (int o = 32; o; o >>= 1) v = fmaxf(v, __shfl_xor(v, o));
  return v;
}
DEV float wave_sum(float v) {
  #pragma unroll
  for (int o = 32; o; o >>= 1) v += __shfl_xor(v, o);
  return v;
}

// grouped packed matvec: Wc = weight base + col*8 (uints); per group g the 8
// k-pairs of this column live at Wc + g*strideG .. +7  (two uint4 loads).
DEV float dotG(const unsigned int* __restrict__ Wc, int strideG,
               const unsigned int* __restrict__ xq, int NG, float init) {
  float a0 = init, a1 = 0.f, a2 = 0.f, a3 = 0.f;
  #pragma unroll 4
  for (int g = 0; g < NG; ++g) {
    uint4 w0 = *reinterpret_cast<const uint4*>(Wc + g * strideG);
    uint4 w1 = *reinterpret_cast<const uint4*>(Wc + g * strideG + 4);
    uint4 x0 = *reinterpret_cast<const uint4*>(xq + g * 8);
    uint4 x1 = *reinterpret_cast<const uint4*>(xq + g * 8 + 4);
    a0 = dot2f(w0.x, x0.x, a0);
    a1 = dot2f(w0.y, x0.y, a1);
    a2 = dot2f(w0.z, x0.z, a2);
    a3 = dot2f(w0.w, x0.w, a3);
    a0 = dot2f(w1.x, x1.x, a0);
    a1 = dot2f(w1.y, x1.y, a1);
    a2 = dot2f(w1.z, x1.z, a2);
    a3 = dot2f(w1.w, x1.w, a3);
  }
  return (a0 + a1) + (a2 + a3);
}

// ---------------- weight f32 -> grouped packed f16 pairs ----------------
// src: [K][Dout] f32 (row-major).  dst: [KPpad/8][Dout][8] packed pairs.
__global__ void pack_wg_kernel(const float* __restrict__ src, unsigned int* __restrict__ dst,
                               int K, int KPpad, int Dout) {
  int idx = blockIdx.x * blockDim.x + threadIdx.x;
  int total = KPpad * Dout;
  if (idx >= total) return;
  int kp = idx / Dout;
  int j  = idx - kp * Dout;
  int r0 = 2 * kp, r1 = r0 + 1;
  float lo = (r0 < K) ? src[r0 * Dout + j] : 0.f;
  float hi = (r1 < K) ? src[r1 * Dout + j] : 0.f;
  int kg = kp >> 3, sub = kp & 7;
  dst[((kg * Dout + j) << 3) + sub] = pack2f(lo, hi);
}

// ---------------- main persistent per-sample kernel ----------------
__global__ __launch_bounds__(512) void fwp_main(
    const float* __restrict__ states, const float* __restrict__ actions,
    const float* __restrict__ tsteps,
    const float* __restrict__ b_ode, const float* __restrict__ b_in,
    const float* __restrict__ ln_in_g, const float* __restrict__ ln_in_b,
    const float* __restrict__ b_q, const float* __restrict__ b_kv,
    const float* __restrict__ b_out,
    const float* __restrict__ ln_ff_g, const float* __restrict__ ln_ff_b,
    const float* __restrict__ b_ff1, const float* __restrict__ b_ff2,
    const float* __restrict__ b_dec,
    const unsigned int* __restrict__ Wode, const unsigned int* __restrict__ Wkv,
    const unsigned int* __restrict__ Win,  const unsigned int* __restrict__ Wq,
    const unsigned int* __restrict__ Wout, const unsigned int* __restrict__ Wff1,
    const unsigned int* __restrict__ Wff2, const unsigned int* __restrict__ Wdec,
    unsigned int* __restrict__ ctrs, float* __restrict__ outp) {

  const int n = blockIdx.x, tid = threadIdx.x;
  const int w = tid >> 6, lane = tid & 63;

  __shared__ alignas(16) float        sh_h[DD];
  __shared__ alignas(16) unsigned int sh_hp[DP];
  __shared__ alignas(16) unsigned int sh_xp[KVKPP];
  __shared__ alignas(16) unsigned int sh_dp[INPG];
  __shared__ alignas(16) float        sh_t[DD];
  __shared__ alignas(16) unsigned int sh_p[DP];
  __shared__ alignas(16) float        sh_kvb[KVO];
  __shared__ alignas(16) float        sh_k[DD];
  __shared__ alignas(16) float        sh_v[DD];
  __shared__ alignas(16) float        sh_q[DD];
  __shared__ float                    sh_lr[HH];
  __shared__ alignas(16) float        sh_ff[FF];
  __shared__ alignas(16) unsigned int sh_ffp[FFP];
  __shared__ float                    sh_red[16];
  __shared__ alignas(16) float        sh_decp[512];
  __shared__ int                      sh_flag;

  float W2r[64];
  #pragma unroll
  for (int i = 0; i < 64; ++i) W2r[i] = 0.f;

  sh_h[tid] = 0.f;
  if (tid < DP) sh_hp[tid] = 0u;
  if (tid >= DP && tid < DP + (KVKPP - KVKP)) sh_xp[KVKP + (tid - DP)] = 0u;  // pad
  if (tid >= 300 && tid < 300 + (INPG - INPP)) sh_dp[INPP + (tid - 300)] = 0u; // pad

  bool pace = true;
  unsigned int* ctr = ctrs + 16 * (n & 7);   // one counter per XCD (blockIdx % 8)

  for (int t = 0; t < TS; ++t) {
    __syncthreads();

    // ---- loose per-XCD pacing barrier (bounded spin; perf-only, deadlock-free)
    if (pace) {
      if (tid == 0) {
        sh_flag = 0;
        __hip_atomic_fetch_add(ctr, 1u, __ATOMIC_RELAXED, __HIP_MEMORY_SCOPE_AGENT);
        unsigned int tgt = 32u * (unsigned int)(t + 1);
        int it = 0;
        while (__hip_atomic_load(ctr, __ATOMIC_RELAXED, __HIP_MEMORY_SCOPE_AGENT) < tgt) {
          if (++it > 4096) { sh_flag = 1; break; }
          __builtin_amdgcn_s_sleep(8);
        }
      }
      __syncthreads();
      if (sh_flag) pace = false;
    }

    // ---- load data (40 inputs -> 20 packed pairs) & dt
    if (tid < INPP) {
      int i0 = 2 * tid, i1 = i0 + 1;
      float a = (i0 < DS) ? states[(n * TS + t) * DS + i0] : actions[(n * TS + t) * DA + (i0 - DS)];
      float b = (i1 < DS) ? states[(n * TS + t) * DS + i1] : actions[(n * TS + t) * DA + (i1 - DS)];
      unsigned int p = pack2f(a, b);
      sh_xp[tid] = p;
      sh_dp[tid] = p;
    }
    const float sdt = 0.25f * (tsteps[n * (TS + 1) + t + 1] - tsteps[n * (TS + 1) + t]);

    // ---- ODE: 4 Euler steps, h += sdt * tanh(h @ W_ode + b_ode)
    for (int e = 0; e < 4; ++e) {
      float acc = dotG(Wode + tid * 8, DD * 8, sh_hp, 32, b_ode[tid]);
      sh_h[tid] += sdt * fast_tanh(acc);      // own element only
      __syncthreads();                        // hp reads done, h written
      if (tid < DP) sh_hp[tid] = pack2f(sh_h[2 * tid], sh_h[2 * tid + 1]);
      __syncthreads();                        // hp ready
    }

    // ---- x = [data, h1] packed
    if (tid < DP) sh_xp[INPP + tid] = sh_hp[tid];
    __syncthreads();

    // ---- kv = x @ W_kv + b_kv   (1032 cols)
    for (int j = tid; j < KVO; j += 512)
      sh_kvb[j] = dotG(Wkv + j * 8, KVO * 8, sh_xp, 35, b_kv[j]);
    __syncthreads();

    // ---- k = softmax(head), v = tanh, lr = sigmoid
    {
      float kx = sh_kvb[tid];
      float km = wave_max(kx);
      float ke = __expf(kx - km);
      float ks = wave_sum(ke);
      sh_k[tid] = ke / ks;
      sh_v[tid] = fast_tanh(sh_kvb[DD + tid]);
      if (tid < HH) sh_lr[tid] = fast_sigmoid(sh_kvb[2 * DD + tid]);
    }

    // ---- q path: LN(data@W_in + b_in) @ W_q + b_q, softmax per head
    float y1 = dotG(Win + tid * 8, DD * 8, sh_dp, 3, b_in[tid]);
    {
      float s1 = y1, s2 = y1 * y1;
      #pragma unroll
      for (int o = 32; o; o >>= 1) { s1 += __shfl_xor(s1, o); s2 += __shfl_xor(s2, o); }
      if (lane == 0) { sh_red[2 * w] = s1; sh_red[2 * w + 1] = s2; }
      __syncthreads();
      s1 = 0.f; s2 = 0.f;
      #pragma unroll
      for (int i = 0; i < 8; ++i) { s1 += sh_red[2 * i]; s2 += sh_red[2 * i + 1]; }
      float m  = s1 * (1.0f / DD);
      float va = fmaxf(s2 * (1.0f / DD) - m * m, 0.f);
      float rs = rsqrtf(va + 1e-5f);
      sh_t[tid] = (y1 - m) * rs * ln_in_g[tid] + ln_in_b[tid];
    }
    __syncthreads();
    if (tid < DP) sh_p[tid] = pack2f(sh_t[2 * tid], sh_t[2 * tid + 1]);
    __syncthreads();
    {
      float qraw = dotG(Wq + tid * 8, DD * 8, sh_p, 32, b_q[tid]);
      float qm = wave_max(qraw);
      float qe = __expf(qraw - qm);
      float qs = wave_sum(qe);
      sh_q[tid] = qe / qs;
    }
    __syncthreads();

    // ---- fused fast-weight update + query (W2 rows in registers)
    {
      float vi  = sh_v[tid];
      float lrw = sh_lr[w];
      float lv  = lrw * vi;
      float acc = 0.f;
      const float* kb = sh_k + w * HD;
      const float* qb = sh_q + w * HD;
      #pragma unroll
      for (int jc = 0; jc < 16; ++jc) {
        float4 k4 = *reinterpret_cast<const float4*>(kb + 4 * jc);
        float4 q4 = *reinterpret_cast<const float4*>(qb + 4 * jc);
        W2r[4 * jc + 0] += lv * k4.x; acc += W2r[4 * jc + 0] * q4.x;
        W2r[4 * jc + 1] += lv * k4.y; acc += W2r[4 * jc + 1] * q4.y;
        W2r[4 * jc + 2] += lv * k4.z; acc += W2r[4 * jc + 2] * q4.z;
        W2r[4 * jc + 3] += lv * k4.w; acc += W2r[4 * jc + 3] * q4.w;
      }
      sh_t[tid] = acc;
    }
    __syncthreads();
    if (tid < DP) sh_p[tid] = pack2f(sh_t[2 * tid], sh_t[2 * tid + 1]);
    __syncthreads();

    // ---- out1 = out @ W_out + b_out
    float o1 = dotG(Wout + tid * 8, DD * 8, sh_p, 32, b_out[tid]);

    // ---- LN_ff
    {
      float s1 = o1, s2 = o1 * o1;
      #pragma unroll
      for (int o = 32; o; o >>= 1) { s1 += __shfl_xor(s1, o); s2 += __shfl_xor(s2, o); }
      if (lane == 0) { sh_red[2 * w] = s1; sh_red[2 * w + 1] = s2; }
      __syncthreads();
      s1 = 0.f; s2 = 0.f;
      #pragma unroll
      for (int i = 0; i < 8; ++i) { s1 += sh_red[2 * i]; s2 += sh_red[2 * i + 1]; }
      float m  = s1 * (1.0f / DD);
      float va = fmaxf(s2 * (1.0f / DD) - m * m, 0.f);
      float rs = rsqrtf(va + 1e-5f);
      sh_t[tid] = (o1 - m) * rs * ln_ff_g[tid] + ln_ff_b[tid];
    }
    __syncthreads();
    if (tid < DP) sh_p[tid] = pack2f(sh_t[2 * tid], sh_t[2 * tid + 1]);
    __syncthreads();

    // ---- FF1 + relu (2048 cols, 4 per thread)
    {
      float f0 = b_ff1[tid], f1 = b_ff1[tid + 512], f2 = b_ff1[tid + 1024], f3 = b_ff1[tid + 1536];
      #pragma unroll 2
      for (int g = 0; g < 32; ++g) {
        uint4 x0 = *reinterpret_cast<const uint4*>(sh_p + g * 8);
        uint4 x1 = *reinterpret_cast<const uint4*>(sh_p + g * 8 + 4);
        const unsigned int* wb = Wff1 + g * (FF * 8) + tid * 8;
        uint4 wa0 = *reinterpret_cast<const uint4*>(wb);
        uint4 wa1 = *reinterpret_cast<const uint4*>(wb + 4);
        uint4 wb0 = *reinterpret_cast<const uint4*>(wb + 512 * 8);
        uint4 wb1 = *reinterpret_cast<const uint4*>(wb + 512 * 8 + 4);
        uint4 wc0 = *reinterpret_cast<const uint4*>(wb + 1024 * 8);
        uint4 wc1 = *reinterpret_cast<const uint4*>(wb + 1024 * 8 + 4);
        uint4 wd0 = *reinterpret_cast<const uint4*>(wb + 1536 * 8);
        uint4 wd1 = *reinterpret_cast<const uint4*>(wb + 1536 * 8 + 4);
        f0 = dot2f(wa0.x, x0.x, f0); f0 = dot2f(wa0.y, x0.y, f0);
        f0 = dot2f(wa0.z, x0.z, f0); f0 = dot2f(wa0.w, x0.w, f0);
        f0 = dot2f(wa1.x, x1.x, f0); f0 = dot2f(wa1.y, x1.y, f0);
        f0 = dot2f(wa1.z, x1.z, f0); f0 = dot2f(wa1.w, x1.w, f0);
        f1 = dot2f(wb0.x, x0.x, f1); f1 = dot2f(wb0.y, x0.y, f1);
        f1 = dot2f(wb0.z, x0.z, f1); f1 = dot2f(wb0.w, x0.w, f1);
        f1 = dot2f(wb1.x, x1.x, f1); f1 = dot2f(wb1.y, x1.y, f1);
        f1 = dot2f(wb1.z, x1.z, f1); f1 = dot2f(wb1.w, x1.w, f1);
        f2 = dot2f(wc0.x, x0.x, f2); f2 = dot2f(wc0.y, x0.y, f2);
        f2 = dot2f(wc0.z, x0.z, f2); f2 = dot2f(wc0.w, x0.w, f2);
        f2 = dot2f(wc1.x, x1.x, f2); f2 = dot2f(wc1.y, x1.y, f2);
        f2 = dot2f(wc1.z, x1.z, f2); f2 = dot2f(wc1.w, x1.w, f2);
        f3 = dot2f(wd0.x, x0.x, f3); f3 = dot2f(wd0.y, x0.y, f3);
        f3 = dot2f(wd0.z, x0.z, f3); f3 = dot2f(wd0.w, x0.w, f3);
        f3 = dot2f(wd1.x, x1.x, f3); f3 = dot2f(wd1.y, x1.y, f3);
        f3 = dot2f(wd1.z, x1.z, f3); f3 = dot2f(wd1.w, x1.w, f3);
      }
      sh_ff[tid]        = fmaxf(f0, 0.f);
      sh_ff[tid + 512]  = fmaxf(f1, 0.f);
      sh_ff[tid + 1024] = fmaxf(f2, 0.f);
      sh_ff[tid + 1536] = fmaxf(f3, 0.f);
    }
    __syncthreads();
    sh_ffp[tid]       = pack2f(sh_ff[2 * tid], sh_ff[2 * tid + 1]);
    sh_ffp[tid + 512] = pack2f(sh_ff[2 * tid + 1024], sh_ff[2 * tid + 1025]);
    __syncthreads();

    // ---- FF2 + bias + residual -> new h1 (carry)
    {
      float o2 = dotG(Wff2 + tid * 8, DD * 8, sh_ffp, 128, b_ff2[tid]) + o1;
      sh_h[tid] = o2;
    }
    __syncthreads();
    if (tid < DP) sh_hp[tid] = pack2f(sh_h[2 * tid], sh_h[2 * tid + 1]);
    __syncthreads();

    // ---- decoder: pred = out @ W_dec + b_dec   (32 cols, 16 k-chunks of 2 groups)
    {
      int col = tid & 31, ch = tid >> 5;
      const unsigned int* wbse = Wdec + col * 8;
      float a = 0.f;
      #pragma unroll
      for (int g = 2 * ch; g < 2 * ch + 2; ++g) {
        uint4 w0 = *reinterpret_cast<const uint4*>(wbse + g * (DS * 8));
        uint4 w1 = *reinterpret_cast<const uint4*>(wbse + g * (DS * 8) + 4);
        uint4 x0 = *reinterpret_cast<const uint4*>(sh_hp + g * 8);
        uint4 x1 = *reinterpret_cast<const uint4*>(sh_hp + g * 8 + 4);
        a = dot2f(w0.x, x0.x, a); a = dot2f(w0.y, x0.y, a);
        a = dot2f(w0.z, x0.z, a); a = dot2f(w0.w, x0.w, a);
        a = dot2f(w1.x, x1.x, a); a = dot2f(w1.y, x1.y, a);
        a = dot2f(w1.z, x1.z, a); a = dot2f(w1.w, x1.w, a);
      }
      sh_decp[tid] = a;
    }
    __syncthreads();
    if (tid < DS) {
      float s = b_dec[tid];
      #pragma unroll
      for (int c = 0; c < 16; ++c) s += sh_decp[c * 32 + tid];
      outp[(n * TS + t) * DS + tid] = s;
    }
  }
}

// ---------------- host launcher ----------------
extern "C" void kernel_launch(void* const* d_in, const int* in_sizes, int n_in,
                              void* d_out, int out_size, void* d_ws, size_t ws_size,
                              hipStream_t stream) {
  (void)in_sizes; (void)n_in; (void)out_size; (void)ws_size;

  const float* states   = (const float*)d_in[0];
  const float* actions  = (const float*)d_in[1];
  const float* tsteps   = (const float*)d_in[2];
  const float* W_ode    = (const float*)d_in[3];
  const float* b_ode    = (const float*)d_in[4];
  const float* W_in     = (const float*)d_in[5];
  const float* b_in     = (const float*)d_in[6];
  const float* ln_in_g  = (const float*)d_in[7];
  const float* ln_in_b  = (const float*)d_in[8];
  const float* W_q      = (const float*)d_in[9];
  const float* b_q      = (const float*)d_in[10];
  const float* W_kv     = (const float*)d_in[11];
  const float* b_kv     = (const float*)d_in[12];
  const float* W_out    = (const float*)d_in[13];
  const float* b_out    = (const float*)d_in[14];
  const float* ln_ff_g  = (const float*)d_in[15];
  const float* ln_ff_b  = (const float*)d_in[16];
  const float* W_ff1    = (const float*)d_in[17];
  const float* b_ff1    = (const float*)d_in[18];
  const float* W_ff2    = (const float*)d_in[19];
  const float* b_ff2    = (const float*)d_in[20];
  const float* W_dec    = (const float*)d_in[21];
  const float* b_dec    = (const float*)d_in[22];

  unsigned int* wsbase = (unsigned int*)d_ws;
  unsigned int* ctrs   = wsbase;           // 8 counters, 64B apart (512B region)
  unsigned int* W      = wsbase + 128;     // packed weights

  hipMemsetAsync(d_ws, 0, 512, stream);

  auto launch_pack = [&](const float* src, unsigned int* dst, int K, int KPpad, int Dout) {
    int total = KPpad * Dout;
    int blocks = (total + 255) / 256;
    pack_wg_kernel<<<blocks, 256, 0, stream>>>(src, dst, K, KPpad, Dout);
  };

  launch_pack(W_ode, W + OFF_ODE, 512,  256, 512);
  launch_pack(W_kv,  W + OFF_KV,  552,  280, 1032);
  launch_pack(W_in,  W + OFF_IN,  40,   24,  512);
  launch_pack(W_q,   W + OFF_Q,   512,  256, 512);
  launch_pack(W_out, W + OFF_OUT, 512,  256, 512);
  launch_pack(W_ff1, W + OFF_F1,  512,  256, 2048);
  launch_pack(W_ff2, W + OFF_F2,  2048, 1024, 512);
  launch_pack(W_dec, W + OFF_DEC, 512,  256, 32);

  fwp_main<<<NS, 512, 0, stream>>>(
      states, actions, tsteps,
      b_ode, b_in, ln_in_g, ln_in_b, b_q, b_kv, b_out, ln_ff_g, ln_ff_b,
      b_ff1, b_ff2, b_dec,
      W + OFF_ODE, W + OFF_KV, W + OFF_IN, W + OFF_Q,
      W + OFF_OUT, W + OFF_F1, W + OFF_F2, W + OFF_DEC,
      ctrs, (float*)d_out);
}